// Round 2
// baseline (457.837 us; speedup 1.0000x reference)
//
#include <hip/hip_runtime.h>
#include <cstdint>
#include <cstddef>

// All external tensors are FP32 (per reference). Internals use bf16 for MFMA.
typedef unsigned short u16;
typedef __attribute__((ext_vector_type(4))) float f32x4;
typedef __attribute__((ext_vector_type(8))) __bf16 bf16x8;
typedef __attribute__((ext_vector_type(8))) unsigned short u16x8;

#define DEV static __device__ __forceinline__

DEV float bf2f(u16 v) { return __uint_as_float(((unsigned)v) << 16); }
DEV u16 f2bf(float f) {
  unsigned u = __float_as_uint(f);
  return (u16)((u + 0x7FFFu + ((u >> 16) & 1u)) >> 16);
}

DEV void gl_lds16(const void* g, void* l) {
  __builtin_amdgcn_global_load_lds((const __attribute__((address_space(1))) void*)g,
                                   (__attribute__((address_space(3))) void*)l, 16, 0, 0);
}

// ---------------------------------------------------------------------------
// 64x64 tiled transpose + fp32->bf16 cast: out[c][r] = bf16(in[r][c]).
// in fp32 [R][incols]; out bf16, row stride 1024. grid=(R/64, C/64), block=256.
__global__ __launch_bounds__(256) void transpose64(const float* __restrict__ in,
                                                   u16* __restrict__ out, int incols) {
  __shared__ __attribute__((aligned(16))) u16 t[64 * 72];
  const int r0 = blockIdx.x * 64, c0 = blockIdx.y * 64, tid = threadIdx.x;
#pragma unroll
  for (int i = 0; i < 2; i++) {
    int c = i * 256 + tid;
    int row = c >> 3, cc = c & 7;
    const float* src = &in[(size_t)(r0 + row) * incols + c0 + cc * 8];
    f32x4 v0 = *(const f32x4*)src;
    f32x4 v1 = *(const f32x4*)(src + 4);
    u16x8 o;
#pragma unroll
    for (int j = 0; j < 4; j++) { o[j] = f2bf(v0[j]); o[4 + j] = f2bf(v1[j]); }
    *(u16x8*)&t[row * 72 + cc * 8] = o;
  }
  __syncthreads();
#pragma unroll
  for (int i = 0; i < 2; i++) {
    int c = i * 256 + tid;
    int d = c >> 3, nc = c & 7;
    u16x8 o;
#pragma unroll
    for (int j = 0; j < 8; j++) o[j] = t[(nc * 8 + j) * 72 + d];
    *(u16x8*)&out[(size_t)(c0 + d) * 1024 + r0 + nc * 8] = o;
  }
}

// ---------------------------------------------------------------------------
// LayerNorm over DIM=1024 (fp32 in, bf16 out), one block per row, block=256.
__global__ __launch_bounds__(256) void ln_x(const float* __restrict__ x,
                                            const float* __restrict__ sc,
                                            const float* __restrict__ bi,
                                            u16* __restrict__ xn) {
  __shared__ float red[8];
  const int row = blockIdx.x, tid = threadIdx.x;
  const int w = tid >> 6;
  f32x4 f = *(const f32x4*)&x[(size_t)row * 1024 + tid * 4];
  float s = f[0] + f[1] + f[2] + f[3];
  float q = f[0] * f[0] + f[1] * f[1] + f[2] * f[2] + f[3] * f[3];
#pragma unroll
  for (int off = 1; off < 64; off <<= 1) {
    s += __shfl_xor(s, off);
    q += __shfl_xor(q, off);
  }
  if ((tid & 63) == 0) { red[w] = s; red[4 + w] = q; }
  __syncthreads();
  float S = red[0] + red[1] + red[2] + red[3];
  float Q = red[4] + red[5] + red[6] + red[7];
  float mu = S * (1.0f / 1024.0f);
  float var = Q * (1.0f / 1024.0f) - mu * mu;
  float rs = rsqrtf(var + 1e-6f);
  f32x4 scv = *(const f32x4*)&sc[tid * 4];
  f32x4 biv = *(const f32x4*)&bi[tid * 4];
  u16* o = xn + (size_t)row * 1024 + tid * 4;
#pragma unroll
  for (int j = 0; j < 4; j++) o[j] = f2bf((f[j] - mu) * rs * scv[j] + biv[j]);
}

// ---------------------------------------------------------------------------
// C[M][N] = A[M][K] * Bt[N][K]^T, bf16 in; out bf16 or fp32 (F32OUT).
// 128x128 tile, BK=32, block=256, global_load_lds width-16 staging.
template <bool F32OUT>
__global__ __launch_bounds__(256) void gemm_bt(const u16* __restrict__ A,
                                               const u16* __restrict__ Bt,
                                               void* __restrict__ Cp,
                                               int M, int N, int K) {
  __shared__ __attribute__((aligned(16))) u16 Als[128 * 32];
  __shared__ __attribute__((aligned(16))) u16 Bls[128 * 32];
  const int tid = threadIdx.x;
  const int w = tid >> 6, lane = tid & 63, ln = lane & 15, quad = lane >> 4;
  const int m0 = blockIdx.y * 128, n0 = blockIdx.x * 128;
  const int moff = (w & 1) * 64, noff = (w >> 1) * 64;
  const f32x4 fzero = {0.f, 0.f, 0.f, 0.f};
  f32x4 acc[4][4];
#pragma unroll
  for (int i = 0; i < 4; i++)
#pragma unroll
    for (int j = 0; j < 4; j++) acc[i][j] = fzero;

  const int c0 = tid, c1 = 256 + tid;
  const u16* aS0 = A + (size_t)(m0 + (c0 >> 2)) * K + (c0 & 3) * 8;
  const u16* aS1 = A + (size_t)(m0 + (c1 >> 2)) * K + (c1 & 3) * 8;
  const u16* bS0 = Bt + (size_t)(n0 + (c0 >> 2)) * K + (c0 & 3) * 8;
  const u16* bS1 = Bt + (size_t)(n0 + (c1 >> 2)) * K + (c1 & 3) * 8;
  u16* aD0 = &Als[c0 * 8]; u16* aD1 = &Als[c1 * 8];
  u16* bD0 = &Bls[c0 * 8]; u16* bD1 = &Bls[c1 * 8];

  for (int k0 = 0; k0 < K; k0 += 32) {
    __syncthreads();
    gl_lds16(aS0 + k0, aD0);
    gl_lds16(aS1 + k0, aD1);
    gl_lds16(bS0 + k0, bD0);
    gl_lds16(bS1 + k0, bD1);
    __syncthreads();
    bf16x8 af[4], bfv[4];
#pragma unroll
    for (int mi = 0; mi < 4; mi++)
      af[mi] = *(const bf16x8*)&Als[(moff + mi * 16 + ln) * 32 + quad * 8];
#pragma unroll
    for (int ni = 0; ni < 4; ni++)
      bfv[ni] = *(const bf16x8*)&Bls[(noff + ni * 16 + ln) * 32 + quad * 8];
#pragma unroll
    for (int mi = 0; mi < 4; mi++)
#pragma unroll
      for (int ni = 0; ni < 4; ni++)
        acc[mi][ni] = __builtin_amdgcn_mfma_f32_16x16x32_bf16(af[mi], bfv[ni],
                                                              acc[mi][ni], 0, 0, 0);
  }
#pragma unroll
  for (int mi = 0; mi < 4; mi++)
#pragma unroll
    for (int ni = 0; ni < 4; ni++)
#pragma unroll
      for (int r = 0; r < 4; r++) {
        size_t m = m0 + moff + mi * 16 + quad * 4 + r;
        size_t n = n0 + noff + ni * 16 + ln;
        if (F32OUT)
          ((float*)Cp)[m * N + n] = acc[mi][ni][r];
        else
          ((u16*)Cp)[m * N + n] = f2bf(acc[mi][ni][r]);
      }
}

// ---------------------------------------------------------------------------
// Per-head LN of q and k slices of qkv[8192][1536] (bf16); fp32 params.
// Writes Q [b][h][n][64] and K [b][g][n][64] (bf16).
__global__ __launch_bounds__(256) void qk_ln(const u16* __restrict__ qkv,
                                             const float* __restrict__ qs,
                                             const float* __restrict__ qb,
                                             const float* __restrict__ ks,
                                             const float* __restrict__ kb,
                                             u16* __restrict__ Q,
                                             u16* __restrict__ Kb) {
  const int m = blockIdx.x;
  const int b = m >> 11, n = m & 2047;
  const int tid = threadIdx.x, w = tid >> 6, lane = tid & 63;
  const u16* rowp = qkv + (size_t)m * 1536;
  const float qsc = qs[lane], qbi = qb[lane];
  const float ksc = ks[lane], kbi = kb[lane];
#pragma unroll
  for (int i = 0; i < 4; i++) {
    int h = w * 4 + i;
    float v = bf2f(rowp[h * 64 + lane]);
    float s = v, q2 = v * v;
#pragma unroll
    for (int off = 1; off < 64; off <<= 1) {
      s += __shfl_xor(s, off);
      q2 += __shfl_xor(q2, off);
    }
    float mu = s * (1.0f / 64.0f);
    float var = q2 * (1.0f / 64.0f) - mu * mu;
    float y = (v - mu) * rsqrtf(var + 1e-6f) * qsc + qbi;
    Q[((size_t)(b * 16 + h) * 2048 + n) * 64 + lane] = f2bf(y);
  }
  {
    int g = w;
    float v = bf2f(rowp[1024 + g * 64 + lane]);
    float s = v, q2 = v * v;
#pragma unroll
    for (int off = 1; off < 64; off <<= 1) {
      s += __shfl_xor(s, off);
      q2 += __shfl_xor(q2, off);
    }
    float mu = s * (1.0f / 64.0f);
    float var = q2 * (1.0f / 64.0f) - mu * mu;
    float y = (v - mu) * rsqrtf(var + 1e-6f) * ksc + kbi;
    Kb[((size_t)(b * 4 + g) * 2048 + n) * 64 + lane] = f2bf(y);
  }
}

// ---------------------------------------------------------------------------
// V transpose: qkv v-slice (bf16 cols 1280+g*64..+63) -> Vt [b][g][64][2048]
// grid = (32, 16), block = 256.
__global__ __launch_bounds__(256) void vtrans(const u16* __restrict__ qkv,
                                              u16* __restrict__ Vt) {
  __shared__ __attribute__((aligned(16))) u16 t[64 * 72];
  const int n0 = blockIdx.x * 64;
  const int bg = blockIdx.y;
  const int b = bg >> 2, g = bg & 3;
  const int tid = threadIdx.x;
  const u16* src = qkv + (size_t)(b * 2048 + n0) * 1536 + 1280 + g * 64;
#pragma unroll
  for (int i = 0; i < 2; i++) {
    int c = i * 256 + tid;
    int row = c >> 3, cc = c & 7;
    *(f32x4*)&t[row * 72 + cc * 8] = *(const f32x4*)&src[(size_t)row * 1536 + cc * 8];
  }
  __syncthreads();
  u16* dst = Vt + (size_t)bg * 64 * 2048 + n0;
#pragma unroll
  for (int i = 0; i < 2; i++) {
    int c = i * 256 + tid;
    int d = c >> 3, nc = c & 7;
    u16x8 o;
#pragma unroll
    for (int j = 0; j < 8; j++) o[j] = t[(nc * 8 + j) * 72 + d];
    *(u16x8*)&dst[(size_t)d * 2048 + nc * 8] = o;
  }
}

// ---------------------------------------------------------------------------
// Flash attention. grid = (16, 64), block = 256 (4 waves, 32 q-rows each).
__global__ __launch_bounds__(256) void attn(const u16* __restrict__ Q,
                                            const u16* __restrict__ Kb,
                                            const u16* __restrict__ Vt,
                                            u16* __restrict__ Out) {
  __shared__ __attribute__((aligned(16))) u16 Kls[128 * 72];
  __shared__ __attribute__((aligned(16))) u16 Vls[64 * 136];
  __shared__ __attribute__((aligned(16))) u16 Pls[4][32 * 136];
  const int qt = blockIdx.x;
  const int bh = blockIdx.y;
  const int b = bh >> 4, h = bh & 15, g = h >> 2;
  const int tid = threadIdx.x, w = tid >> 6, lane = tid & 63;
  const int ln = lane & 15, quad = lane >> 4;
  const u16* Qg = Q + ((size_t)(b * 16 + h) * 2048 + qt * 128 + w * 32) * 64;
  const u16* Kg = Kb + (size_t)(b * 4 + g) * 2048 * 64;
  const u16* Vg = Vt + (size_t)(b * 4 + g) * 64 * 2048;
  const f32x4 fzero = {0.f, 0.f, 0.f, 0.f};
  const float sc = 0.18033688f;  // 0.125 * log2(e)

  bf16x8 qf[2][2];
#pragma unroll
  for (int mi = 0; mi < 2; mi++)
#pragma unroll
    for (int ks2 = 0; ks2 < 2; ks2++)
      qf[mi][ks2] = *(const bf16x8*)&Qg[(size_t)(mi * 16 + ln) * 64 + ks2 * 32 + quad * 8];

  f32x4 oacc[2][4];
  float m2[2][4], lsum[2][4];
#pragma unroll
  for (int mi = 0; mi < 2; mi++)
#pragma unroll
    for (int r = 0; r < 4; r++) { m2[mi][r] = -3.0e38f; lsum[mi][r] = 0.f; }
#pragma unroll
  for (int mi = 0; mi < 2; mi++)
#pragma unroll
    for (int ni = 0; ni < 4; ni++) oacc[mi][ni] = fzero;

  u16* Pw = &Pls[w][0];

  for (int kt = 0; kt < 16; kt++) {
    __syncthreads();
#pragma unroll
    for (int i = 0; i < 4; i++) {
      int c = i * 256 + tid;
      int row = c >> 3, cc = c & 7;
      *(f32x4*)&Kls[row * 72 + cc * 8] =
          *(const f32x4*)&Kg[((size_t)kt * 128 + row) * 64 + cc * 8];
    }
#pragma unroll
    for (int i = 0; i < 4; i++) {
      int c = i * 256 + tid;
      int row = c >> 4, cc = c & 15;
      *(f32x4*)&Vls[row * 136 + cc * 8] =
          *(const f32x4*)&Vg[(size_t)row * 2048 + kt * 128 + cc * 8];
    }
    __syncthreads();

    // S = Q K^T  (wave: 32 x 128)
    f32x4 sacc[2][8];
#pragma unroll
    for (int ni = 0; ni < 8; ni++) {
      bf16x8 kf0 = *(const bf16x8*)&Kls[(ni * 16 + ln) * 72 + quad * 8];
      bf16x8 kf1 = *(const bf16x8*)&Kls[(ni * 16 + ln) * 72 + 32 + quad * 8];
#pragma unroll
      for (int mi = 0; mi < 2; mi++) {
        f32x4 tt = __builtin_amdgcn_mfma_f32_16x16x32_bf16(qf[mi][0], kf0, fzero, 0, 0, 0);
        sacc[mi][ni] = __builtin_amdgcn_mfma_f32_16x16x32_bf16(qf[mi][1], kf1, tt, 0, 0, 0);
      }
    }

    // online softmax (exp2 domain); row stats live in a 16-lane quad group
    float alpha[2][4];
#pragma unroll
    for (int mi = 0; mi < 2; mi++)
#pragma unroll
      for (int r = 0; r < 4; r++) {
        float mx = -3.0e38f;
#pragma unroll
        for (int ni = 0; ni < 8; ni++) {
          float s = sacc[mi][ni][r] * sc;
          sacc[mi][ni][r] = s;
          mx = fmaxf(mx, s);
        }
        mx = fmaxf(mx, __shfl_xor(mx, 1));
        mx = fmaxf(mx, __shfl_xor(mx, 2));
        mx = fmaxf(mx, __shfl_xor(mx, 4));
        mx = fmaxf(mx, __shfl_xor(mx, 8));
        float mn = fmaxf(m2[mi][r], mx);
        float a = exp2f(m2[mi][r] - mn);
        m2[mi][r] = mn;
        float ps = 0.f;
#pragma unroll
        for (int ni = 0; ni < 8; ni++) {
          float p = exp2f(sacc[mi][ni][r] - mn);
          sacc[mi][ni][r] = p;
          ps += p;
        }
        ps += __shfl_xor(ps, 1);
        ps += __shfl_xor(ps, 2);
        ps += __shfl_xor(ps, 4);
        ps += __shfl_xor(ps, 8);
        lsum[mi][r] = lsum[mi][r] * a + ps;
        alpha[mi][r] = a;
      }
#pragma unroll
    for (int mi = 0; mi < 2; mi++)
#pragma unroll
      for (int ni = 0; ni < 4; ni++)
#pragma unroll
        for (int r = 0; r < 4; r++) oacc[mi][ni][r] *= alpha[mi][r];

    // P -> LDS (bf16), wave-private region, padded stride 136
#pragma unroll
    for (int mi = 0; mi < 2; mi++)
#pragma unroll
      for (int ni = 0; ni < 8; ni++)
#pragma unroll
        for (int r = 0; r < 4; r++)
          Pw[(mi * 16 + quad * 4 + r) * 136 + ni * 16 + ln] = f2bf(sacc[mi][ni][r]);
    __syncthreads();

    // O += P V  (K-dim = 128 keys)
#pragma unroll
    for (int kc = 0; kc < 4; kc++) {
      bf16x8 pf0 = *(const bf16x8*)&Pw[(size_t)ln * 136 + kc * 32 + quad * 8];
      bf16x8 pf1 = *(const bf16x8*)&Pw[(size_t)(16 + ln) * 136 + kc * 32 + quad * 8];
#pragma unroll
      for (int ni = 0; ni < 4; ni++) {
        bf16x8 vf = *(const bf16x8*)&Vls[(ni * 16 + ln) * 136 + kc * 32 + quad * 8];
        oacc[0][ni] = __builtin_amdgcn_mfma_f32_16x16x32_bf16(pf0, vf, oacc[0][ni], 0, 0, 0);
        oacc[1][ni] = __builtin_amdgcn_mfma_f32_16x16x32_bf16(pf1, vf, oacc[1][ni], 0, 0, 0);
      }
    }
  }

  u16* Og = Out + ((size_t)b * 2048 + qt * 128 + w * 32) * 1024 + h * 64;
#pragma unroll
  for (int mi = 0; mi < 2; mi++)
#pragma unroll
    for (int r = 0; r < 4; r++) {
      float inv = 1.0f / lsum[mi][r];
#pragma unroll
      for (int ni = 0; ni < 4; ni++)
        Og[(size_t)(mi * 16 + quad * 4 + r) * 1024 + ni * 16 + ln] =
            f2bf(oacc[mi][ni][r] * inv);
    }
}

// ---------------------------------------------------------------------------
extern "C" void kernel_launch(void* const* d_in, const int* in_sizes, int n_in,
                              void* d_out, int out_size, void* d_ws, size_t ws_size,
                              hipStream_t stream) {
  const float* x    = (const float*)d_in[0];
  const float* lns  = (const float*)d_in[1];
  const float* lnb  = (const float*)d_in[2];
  const float* Wq   = (const float*)d_in[3];
  const float* Wkv  = (const float*)d_in[4];
  const float* qns  = (const float*)d_in[5];
  const float* qnb  = (const float*)d_in[6];
  const float* kns  = (const float*)d_in[7];
  const float* knb  = (const float*)d_in[8];
  const float* Wout = (const float*)d_in[9];
  float* out = (float*)d_out;
  char* ws = (char*)d_ws;

  // workspace layout (bytes), with region reuse
  const size_t o_xn  = 0;                 // 16 MB: xn (bf16), later Qbuf
  const size_t o_qkv = 16777216;          // 24 MB: qkv (bf16), later attn_out
  const size_t o_bt  = o_qkv + 25165824;  // 3 MB: W^T (bf16), reused for Wout^T
  const size_t o_k   = o_bt + 3145728;    // 4 MB: Kbuf
  const size_t o_vt  = o_k + 4194304;     // 4 MB: Vtbuf
  u16* xn   = (u16*)(ws + o_xn);
  u16* qkv  = (u16*)(ws + o_qkv);
  u16* bt   = (u16*)(ws + o_bt);
  u16* Kbuf = (u16*)(ws + o_k);
  u16* Vtb  = (u16*)(ws + o_vt);
  u16* Qbuf = xn;    // xn dead after GEMM1
  u16* aout = qkv;   // qkv dead after qk_ln/vtrans

  transpose64<<<dim3(16, 16), 256, 0, stream>>>(Wq, bt, 1024);
  transpose64<<<dim3(16, 8), 256, 0, stream>>>(Wkv, bt + 1024 * 1024, 512);
  ln_x<<<8192, 256, 0, stream>>>(x, lns, lnb, xn);
  gemm_bt<false><<<dim3(12, 64), 256, 0, stream>>>(xn, bt, qkv, 8192, 1536, 1024);
  transpose64<<<dim3(16, 16), 256, 0, stream>>>(Wout, bt, 1024);
  qk_ln<<<8192, 256, 0, stream>>>(qkv, qns, qnb, kns, knb, Qbuf, Kbuf);
  vtrans<<<dim3(32, 16), 256, 0, stream>>>(qkv, Vtb);
  attn<<<dim3(16, 64), 256, 0, stream>>>(Qbuf, Kbuf, Vtb, aout);
  gemm_bt<true><<<dim3(8, 64), 256, 0, stream>>>(aout, bt, out, 8192, 1024, 1024);

  (void)in_sizes; (void)n_in; (void)out_size; (void)ws_size;
}

// Round 3
// 297.921 us; speedup vs baseline: 1.5368x; 1.5368x over previous
//
#include <hip/hip_runtime.h>
#include <cstdint>
#include <cstddef>

// All external tensors are FP32 (per reference). Internals use bf16 for MFMA.
typedef unsigned short u16;
typedef __attribute__((ext_vector_type(4))) float f32x4;
typedef __attribute__((ext_vector_type(8))) __bf16 bf16x8;
typedef __attribute__((ext_vector_type(4))) __bf16 bf16x4;
typedef __attribute__((ext_vector_type(8))) unsigned short u16x8;

#define DEV static __device__ __forceinline__

#if __has_builtin(__builtin_amdgcn_exp2f)
#define EXP2(x) __builtin_amdgcn_exp2f(x)
#else
#define EXP2(x) exp2f(x)
#endif

DEV float bf2f(u16 v) { return __uint_as_float(((unsigned)v) << 16); }
DEV u16 f2bf(float f) {
  unsigned u = __float_as_uint(f);
  return (u16)((u + 0x7FFFu + ((u >> 16) & 1u)) >> 16);
}

DEV void gl_lds16(const void* g, void* l) {
  __builtin_amdgcn_global_load_lds((const __attribute__((address_space(1))) void*)g,
                                   (__attribute__((address_space(3))) void*)l, 16, 0, 0);
}

// ---------------------------------------------------------------------------
// 64x64 tiled transpose + fp32->bf16 cast: out[c][r] = bf16(in[r][c]).
__global__ __launch_bounds__(256) void transpose64(const float* __restrict__ in,
                                                   u16* __restrict__ out, int incols) {
  __shared__ __attribute__((aligned(16))) u16 t[64 * 72];
  const int r0 = blockIdx.x * 64, c0 = blockIdx.y * 64, tid = threadIdx.x;
#pragma unroll
  for (int i = 0; i < 2; i++) {
    int c = i * 256 + tid;
    int row = c >> 3, cc = c & 7;
    const float* src = &in[(size_t)(r0 + row) * incols + c0 + cc * 8];
    f32x4 v0 = *(const f32x4*)src;
    f32x4 v1 = *(const f32x4*)(src + 4);
    u16x8 o;
#pragma unroll
    for (int j = 0; j < 4; j++) { o[j] = f2bf(v0[j]); o[4 + j] = f2bf(v1[j]); }
    *(u16x8*)&t[row * 72 + cc * 8] = o;
  }
  __syncthreads();
#pragma unroll
  for (int i = 0; i < 2; i++) {
    int c = i * 256 + tid;
    int d = c >> 3, nc = c & 7;
    u16x8 o;
#pragma unroll
    for (int j = 0; j < 8; j++) o[j] = t[(nc * 8 + j) * 72 + d];
    *(u16x8*)&out[(size_t)(c0 + d) * 1024 + r0 + nc * 8] = o;
  }
}

// ---------------------------------------------------------------------------
// LayerNorm over DIM=1024 (fp32 in, bf16 out), one block per row.
__global__ __launch_bounds__(256) void ln_x(const float* __restrict__ x,
                                            const float* __restrict__ sc,
                                            const float* __restrict__ bi,
                                            u16* __restrict__ xn) {
  __shared__ float red[8];
  const int row = blockIdx.x, tid = threadIdx.x;
  const int w = tid >> 6;
  f32x4 f = *(const f32x4*)&x[(size_t)row * 1024 + tid * 4];
  float s = f[0] + f[1] + f[2] + f[3];
  float q = f[0] * f[0] + f[1] * f[1] + f[2] * f[2] + f[3] * f[3];
#pragma unroll
  for (int off = 1; off < 64; off <<= 1) {
    s += __shfl_xor(s, off);
    q += __shfl_xor(q, off);
  }
  if ((tid & 63) == 0) { red[w] = s; red[4 + w] = q; }
  __syncthreads();
  float S = red[0] + red[1] + red[2] + red[3];
  float Q = red[4] + red[5] + red[6] + red[7];
  float mu = S * (1.0f / 1024.0f);
  float var = Q * (1.0f / 1024.0f) - mu * mu;
  float rs = rsqrtf(var + 1e-6f);
  f32x4 scv = *(const f32x4*)&sc[tid * 4];
  f32x4 biv = *(const f32x4*)&bi[tid * 4];
  u16* o = xn + (size_t)row * 1024 + tid * 4;
#pragma unroll
  for (int j = 0; j < 4; j++) o[j] = f2bf((f[j] - mu) * rs * scv[j] + biv[j]);
}

// ---------------------------------------------------------------------------
// C[M][N] = A[M][K] * Bt[N][K]^T, bf16 in; out bf16 or fp32 (F32OUT).
template <bool F32OUT>
__global__ __launch_bounds__(256) void gemm_bt(const u16* __restrict__ A,
                                               const u16* __restrict__ Bt,
                                               void* __restrict__ Cp,
                                               int M, int N, int K) {
  __shared__ __attribute__((aligned(16))) u16 Als[128 * 32];
  __shared__ __attribute__((aligned(16))) u16 Bls[128 * 32];
  const int tid = threadIdx.x;
  const int w = tid >> 6, lane = tid & 63, ln = lane & 15, quad = lane >> 4;
  const int m0 = blockIdx.y * 128, n0 = blockIdx.x * 128;
  const int moff = (w & 1) * 64, noff = (w >> 1) * 64;
  const f32x4 fzero = {0.f, 0.f, 0.f, 0.f};
  f32x4 acc[4][4];
#pragma unroll
  for (int i = 0; i < 4; i++)
#pragma unroll
    for (int j = 0; j < 4; j++) acc[i][j] = fzero;

  const int c0 = tid, c1 = 256 + tid;
  const u16* aS0 = A + (size_t)(m0 + (c0 >> 2)) * K + (c0 & 3) * 8;
  const u16* aS1 = A + (size_t)(m0 + (c1 >> 2)) * K + (c1 & 3) * 8;
  const u16* bS0 = Bt + (size_t)(n0 + (c0 >> 2)) * K + (c0 & 3) * 8;
  const u16* bS1 = Bt + (size_t)(n0 + (c1 >> 2)) * K + (c1 & 3) * 8;
  u16* aD0 = &Als[c0 * 8]; u16* aD1 = &Als[c1 * 8];
  u16* bD0 = &Bls[c0 * 8]; u16* bD1 = &Bls[c1 * 8];

  for (int k0 = 0; k0 < K; k0 += 32) {
    __syncthreads();
    gl_lds16(aS0 + k0, aD0);
    gl_lds16(aS1 + k0, aD1);
    gl_lds16(bS0 + k0, bD0);
    gl_lds16(bS1 + k0, bD1);
    __syncthreads();
    bf16x8 af[4], bfv[4];
#pragma unroll
    for (int mi = 0; mi < 4; mi++)
      af[mi] = *(const bf16x8*)&Als[(moff + mi * 16 + ln) * 32 + quad * 8];
#pragma unroll
    for (int ni = 0; ni < 4; ni++)
      bfv[ni] = *(const bf16x8*)&Bls[(noff + ni * 16 + ln) * 32 + quad * 8];
#pragma unroll
    for (int mi = 0; mi < 4; mi++)
#pragma unroll
      for (int ni = 0; ni < 4; ni++)
        acc[mi][ni] = __builtin_amdgcn_mfma_f32_16x16x32_bf16(af[mi], bfv[ni],
                                                              acc[mi][ni], 0, 0, 0);
  }
#pragma unroll
  for (int mi = 0; mi < 4; mi++)
#pragma unroll
    for (int ni = 0; ni < 4; ni++)
#pragma unroll
      for (int r = 0; r < 4; r++) {
        size_t m = m0 + moff + mi * 16 + quad * 4 + r;
        size_t n = n0 + noff + ni * 16 + ln;
        if (F32OUT)
          ((float*)Cp)[m * N + n] = acc[mi][ni][r];
        else
          ((u16*)Cp)[m * N + n] = f2bf(acc[mi][ni][r]);
      }
}

// ---------------------------------------------------------------------------
// Per-head LN of q and k slices of qkv[8192][1536] (bf16); fp32 params.
// Q is pre-scaled by 0.125*log2(e) so attention scores are directly in the
// exp2 domain (fixed-max softmax; |score| <= ~11.5 so no overflow).
__global__ __launch_bounds__(256) void qk_ln(const u16* __restrict__ qkv,
                                             const float* __restrict__ qs,
                                             const float* __restrict__ qb,
                                             const float* __restrict__ ks,
                                             const float* __restrict__ kb,
                                             u16* __restrict__ Q,
                                             u16* __restrict__ Kb) {
  const float SCL = 0.18033688011112042f;  // 0.125 * log2(e)
  const int m = blockIdx.x;
  const int b = m >> 11, n = m & 2047;
  const int tid = threadIdx.x, w = tid >> 6, lane = tid & 63;
  const u16* rowp = qkv + (size_t)m * 1536;
  const float qsc = qs[lane], qbi = qb[lane];
  const float ksc = ks[lane], kbi = kb[lane];
#pragma unroll
  for (int i = 0; i < 4; i++) {
    int h = w * 4 + i;
    float v = bf2f(rowp[h * 64 + lane]);
    float s = v, q2 = v * v;
#pragma unroll
    for (int off = 1; off < 64; off <<= 1) {
      s += __shfl_xor(s, off);
      q2 += __shfl_xor(q2, off);
    }
    float mu = s * (1.0f / 64.0f);
    float var = q2 * (1.0f / 64.0f) - mu * mu;
    float y = ((v - mu) * rsqrtf(var + 1e-6f) * qsc + qbi) * SCL;
    Q[((size_t)(b * 16 + h) * 2048 + n) * 64 + lane] = f2bf(y);
  }
  {
    int g = w;
    float v = bf2f(rowp[1024 + g * 64 + lane]);
    float s = v, q2 = v * v;
#pragma unroll
    for (int off = 1; off < 64; off <<= 1) {
      s += __shfl_xor(s, off);
      q2 += __shfl_xor(q2, off);
    }
    float mu = s * (1.0f / 64.0f);
    float var = q2 * (1.0f / 64.0f) - mu * mu;
    float y = (v - mu) * rsqrtf(var + 1e-6f) * ksc + kbi;
    Kb[((size_t)(b * 4 + g) * 2048 + n) * 64 + lane] = f2bf(y);
  }
}

// ---------------------------------------------------------------------------
// V transpose: qkv v-slice -> Vt [b][g][64][2048]. grid = (32, 16).
__global__ __launch_bounds__(256) void vtrans(const u16* __restrict__ qkv,
                                              u16* __restrict__ Vt) {
  __shared__ __attribute__((aligned(16))) u16 t[64 * 72];
  const int n0 = blockIdx.x * 64;
  const int bg = blockIdx.y;
  const int b = bg >> 2, g = bg & 3;
  const int tid = threadIdx.x;
  const u16* src = qkv + (size_t)(b * 2048 + n0) * 1536 + 1280 + g * 64;
#pragma unroll
  for (int i = 0; i < 2; i++) {
    int c = i * 256 + tid;
    int row = c >> 3, cc = c & 7;
    *(f32x4*)&t[row * 72 + cc * 8] = *(const f32x4*)&src[(size_t)row * 1536 + cc * 8];
  }
  __syncthreads();
  u16* dst = Vt + (size_t)bg * 64 * 2048 + n0;
#pragma unroll
  for (int i = 0; i < 2; i++) {
    int c = i * 256 + tid;
    int d = c >> 3, nc = c & 7;
    u16x8 o;
#pragma unroll
    for (int j = 0; j < 8; j++) o[j] = t[(nc * 8 + j) * 72 + d];
    *(u16x8*)&dst[(size_t)d * 2048 + nc * 8] = o;
  }
}

// ---------------------------------------------------------------------------
// Flash attention, transposed-S orientation, fixed-max softmax.
// grid = (16, 64), block = 256 (4 waves, 32 q-rows each).
// S^T = mfma(A=K, B=Q): col = m = ln (per-lane row stats), row = key.
// O^T = mfma(A=Vt, B=P): col = m = ln, row = d.
// K/V/P in LDS with 16B-chunk XOR swizzle (2-way max conflicts); K/V staged
// via global_load_lds (lane-ordered dest, per-lane swizzled source).
__global__ __launch_bounds__(256) void attn(const u16* __restrict__ Q,
                                            const u16* __restrict__ Kb,
                                            const u16* __restrict__ Vt,
                                            u16* __restrict__ Out) {
  __shared__ __attribute__((aligned(16))) u16 Kls[128 * 64];   // [key][d], swizzled
  __shared__ __attribute__((aligned(16))) u16 Vls[64 * 128];   // [d][key], swizzled
  __shared__ __attribute__((aligned(16))) u16 Pls[4][32 * 128];// per-wave [m][key]
  const int qt = blockIdx.x;
  const int bh = blockIdx.y;
  const int b = bh >> 4, h = bh & 15, g = h >> 2;
  const int tid = threadIdx.x, w = tid >> 6, lane = tid & 63;
  const int ln = lane & 15, quad = lane >> 4;
  const u16* Qg = Q + ((size_t)(b * 16 + h) * 2048 + qt * 128 + w * 32) * 64;
  const u16* Kg = Kb + (size_t)(b * 4 + g) * 2048 * 64;
  const u16* Vg = Vt + (size_t)(b * 4 + g) * 64 * 2048;
  const f32x4 fzero = {0.f, 0.f, 0.f, 0.f};

  // Q fragments (B-operand): rows m = mi*16+ln, k(d) = ks2*32 + quad*8
  bf16x8 qf[2][2];
#pragma unroll
  for (int mi = 0; mi < 2; mi++)
#pragma unroll
    for (int ks2 = 0; ks2 < 2; ks2++)
      qf[mi][ks2] = *(const bf16x8*)&Qg[(size_t)(mi * 16 + ln) * 64 + ks2 * 32 + quad * 8];

  f32x4 oacc[4][2];  // [ni(d-tile)][mi(m-tile)]
#pragma unroll
  for (int ni = 0; ni < 4; ni++)
#pragma unroll
    for (int mi = 0; mi < 2; mi++) oacc[ni][mi] = fzero;
  float lsum[2] = {0.f, 0.f};
  u16* Pw = &Pls[w][0];

  for (int kt = 0; kt < 16; kt++) {
    __syncthreads();
    // stage K tile [128 keys][64 d] (contiguous 16KB in global), XOR-swizzled:
    // LDS chunk slot s holds global chunk ( (s&7) ^ ((s>>3)&7) ) of row s>>3.
#pragma unroll
    for (int i = 0; i < 4; i++) {
      int s = i * 256 + tid;
      int key = s >> 3, cs = (s & 7) ^ (key & 7);
      gl_lds16(Kg + (size_t)kt * 8192 + key * 64 + cs * 8, &Kls[s * 8]);
    }
    // stage Vt tile [64 d][128 keys], XOR-swizzled on 16 chunks/row
#pragma unroll
    for (int i = 0; i < 4; i++) {
      int s = i * 256 + tid;
      int d = s >> 4, cs = (s & 15) ^ (d & 15);
      gl_lds16(Vg + (size_t)d * 2048 + kt * 128 + cs * 8, &Vls[s * 8]);
    }
    __syncthreads();

    // S^T: sacc[mi][ni][r] = S[key=ni*16+quad*4+r][m=mi*16+ln] (exp2 domain)
    f32x4 sacc[2][8];
#pragma unroll
    for (int ni = 0; ni < 8; ni++) {
      const int krow = ni * 16 + ln;
      bf16x8 kf0 = *(const bf16x8*)&Kls[krow * 64 + ((quad ^ (krow & 7)) * 8)];
      bf16x8 kf1 = *(const bf16x8*)&Kls[krow * 64 + (((4 + quad) ^ (krow & 7)) * 8)];
#pragma unroll
      for (int mi = 0; mi < 2; mi++) {
        f32x4 tt = __builtin_amdgcn_mfma_f32_16x16x32_bf16(kf0, qf[mi][0], fzero, 0, 0, 0);
        sacc[mi][ni] = __builtin_amdgcn_mfma_f32_16x16x32_bf16(kf1, qf[mi][1], tt, 0, 0, 0);
      }
    }

    // fixed-max softmax: p = exp2(s); accumulate row sums (row = m = ln per lane)
#pragma unroll
    for (int mi = 0; mi < 2; mi++) {
      float ls = 0.f;
      const int mrow = mi * 16 + ln;
#pragma unroll
      for (int ni = 0; ni < 8; ni++) {
        float p0 = EXP2(sacc[mi][ni][0]);
        float p1 = EXP2(sacc[mi][ni][1]);
        float p2 = EXP2(sacc[mi][ni][2]);
        float p3 = EXP2(sacc[mi][ni][3]);
        ls += (p0 + p1) + (p2 + p3);
        bf16x4 pv = {(__bf16)p0, (__bf16)p1, (__bf16)p2, (__bf16)p3};
        // keys ni*16+quad*4+{0..3} -> 16B chunk (2ni + quad/2) ^ ln, half (quad&1)
        char* dst = (char*)&Pw[mrow * 128] +
                    (((2 * ni + (quad >> 1)) ^ ln) * 16) + ((quad & 1) * 8);
        *(bf16x4*)dst = pv;
      }
      ls += __shfl_xor(ls, 16);
      ls += __shfl_xor(ls, 32);
      lsum[mi] += ls;
    }

    // O^T += Vt * P^T   (A = V-frag rows d, B = P-frag rows m)
#pragma unroll
    for (int kc = 0; kc < 4; kc++) {
      bf16x8 pf[2];
#pragma unroll
      for (int mi = 0; mi < 2; mi++)
        pf[mi] = *(const bf16x8*)&Pw[(mi * 16 + ln) * 128 + (((4 * kc + quad) ^ ln) * 8)];
#pragma unroll
      for (int ni = 0; ni < 4; ni++) {
        const int drow = ni * 16 + ln;
        bf16x8 vf = *(const bf16x8*)&Vls[drow * 128 + (((4 * kc + quad) ^ ln) * 8)];
#pragma unroll
        for (int mi = 0; mi < 2; mi++)
          oacc[ni][mi] = __builtin_amdgcn_mfma_f32_16x16x32_bf16(vf, pf[mi],
                                                                 oacc[ni][mi], 0, 0, 0);
      }
    }
  }

  // epilogue: O[m][d] = O^T / lsum; row n = qt*128 + w*32 + mi*16 + ln
#pragma unroll
  for (int mi = 0; mi < 2; mi++) {
    float inv = 1.0f / lsum[mi];
    u16* Og = Out + ((size_t)b * 2048 + qt * 128 + w * 32 + mi * 16 + ln) * 1024 + h * 64;
#pragma unroll
    for (int ni = 0; ni < 4; ni++) {
      bf16x4 ov = {(__bf16)(oacc[ni][mi][0] * inv), (__bf16)(oacc[ni][mi][1] * inv),
                   (__bf16)(oacc[ni][mi][2] * inv), (__bf16)(oacc[ni][mi][3] * inv)};
      *(bf16x4*)&Og[ni * 16 + quad * 4] = ov;
    }
  }
}

// ---------------------------------------------------------------------------
extern "C" void kernel_launch(void* const* d_in, const int* in_sizes, int n_in,
                              void* d_out, int out_size, void* d_ws, size_t ws_size,
                              hipStream_t stream) {
  const float* x    = (const float*)d_in[0];
  const float* lns  = (const float*)d_in[1];
  const float* lnb  = (const float*)d_in[2];
  const float* Wq   = (const float*)d_in[3];
  const float* Wkv  = (const float*)d_in[4];
  const float* qns  = (const float*)d_in[5];
  const float* qnb  = (const float*)d_in[6];
  const float* kns  = (const float*)d_in[7];
  const float* knb  = (const float*)d_in[8];
  const float* Wout = (const float*)d_in[9];
  float* out = (float*)d_out;
  char* ws = (char*)d_ws;

  const size_t o_xn  = 0;                 // 16 MB: xn (bf16), later Qbuf
  const size_t o_qkv = 16777216;          // 24 MB: qkv (bf16), later attn_out
  const size_t o_bt  = o_qkv + 25165824;  // 3 MB: W^T (bf16), reused for Wout^T
  const size_t o_k   = o_bt + 3145728;    // 4 MB: Kbuf
  const size_t o_vt  = o_k + 4194304;     // 4 MB: Vtbuf
  u16* xn   = (u16*)(ws + o_xn);
  u16* qkv  = (u16*)(ws + o_qkv);
  u16* bt   = (u16*)(ws + o_bt);
  u16* Kbuf = (u16*)(ws + o_k);
  u16* Vtb  = (u16*)(ws + o_vt);
  u16* Qbuf = xn;    // xn dead after GEMM1
  u16* aout = qkv;   // qkv dead after qk_ln/vtrans

  transpose64<<<dim3(16, 16), 256, 0, stream>>>(Wq, bt, 1024);
  transpose64<<<dim3(16, 8), 256, 0, stream>>>(Wkv, bt + 1024 * 1024, 512);
  ln_x<<<8192, 256, 0, stream>>>(x, lns, lnb, xn);
  gemm_bt<false><<<dim3(12, 64), 256, 0, stream>>>(xn, bt, qkv, 8192, 1536, 1024);
  transpose64<<<dim3(16, 16), 256, 0, stream>>>(Wout, bt, 1024);
  qk_ln<<<8192, 256, 0, stream>>>(qkv, qns, qnb, kns, knb, Qbuf, Kbuf);
  vtrans<<<dim3(32, 16), 256, 0, stream>>>(qkv, Vtb);
  attn<<<dim3(16, 64), 256, 0, stream>>>(Qbuf, Kbuf, Vtb, aout);
  gemm_bt<true><<<dim3(8, 64), 256, 0, stream>>>(aout, bt, out, 8192, 1024, 1024);

  (void)in_sizes; (void)n_in; (void)out_size; (void)ws_size;
}

// Round 4
// 292.513 us; speedup vs baseline: 1.5652x; 1.0185x over previous
//
#include <hip/hip_runtime.h>
#include <cstdint>
#include <cstddef>

// All external tensors are FP32 (per reference). Internals use bf16 for MFMA.
typedef unsigned short u16;
typedef __attribute__((ext_vector_type(4))) float f32x4;
typedef __attribute__((ext_vector_type(8))) __bf16 bf16x8;
typedef __attribute__((ext_vector_type(4))) __bf16 bf16x4;
typedef __attribute__((ext_vector_type(8))) unsigned short u16x8;

#define DEV static __device__ __forceinline__

#if __has_builtin(__builtin_amdgcn_exp2f)
#define EXP2(x) __builtin_amdgcn_exp2f(x)
#else
#define EXP2(x) exp2f(x)
#endif

DEV float bf2f(u16 v) { return __uint_as_float(((unsigned)v) << 16); }
DEV u16 f2bf(float f) {
  unsigned u = __float_as_uint(f);
  return (u16)((u + 0x7FFFu + ((u >> 16) & 1u)) >> 16);
}

DEV void gl_lds16(const void* g, void* l) {
  __builtin_amdgcn_global_load_lds((const __attribute__((address_space(1))) void*)g,
                                   (__attribute__((address_space(3))) void*)l, 16, 0, 0);
}

// ---------------------------------------------------------------------------
// 64x64 tiled transpose + fp32->bf16 cast: out[c][r] = bf16(in[r][c]).
__global__ __launch_bounds__(256) void transpose64(const float* __restrict__ in,
                                                   u16* __restrict__ out, int incols) {
  __shared__ __attribute__((aligned(16))) u16 t[64 * 72];
  const int r0 = blockIdx.x * 64, c0 = blockIdx.y * 64, tid = threadIdx.x;
#pragma unroll
  for (int i = 0; i < 2; i++) {
    int c = i * 256 + tid;
    int row = c >> 3, cc = c & 7;
    const float* src = &in[(size_t)(r0 + row) * incols + c0 + cc * 8];
    f32x4 v0 = *(const f32x4*)src;
    f32x4 v1 = *(const f32x4*)(src + 4);
    u16x8 o;
#pragma unroll
    for (int j = 0; j < 4; j++) { o[j] = f2bf(v0[j]); o[4 + j] = f2bf(v1[j]); }
    *(u16x8*)&t[row * 72 + cc * 8] = o;
  }
  __syncthreads();
#pragma unroll
  for (int i = 0; i < 2; i++) {
    int c = i * 256 + tid;
    int d = c >> 3, nc = c & 7;
    u16x8 o;
#pragma unroll
    for (int j = 0; j < 8; j++) o[j] = t[(nc * 8 + j) * 72 + d];
    *(u16x8*)&out[(size_t)(c0 + d) * 1024 + r0 + nc * 8] = o;
  }
}

// ---------------------------------------------------------------------------
// LayerNorm over DIM=1024 (fp32 in, bf16 out), one block per row.
__global__ __launch_bounds__(256) void ln_x(const float* __restrict__ x,
                                            const float* __restrict__ sc,
                                            const float* __restrict__ bi,
                                            u16* __restrict__ xn) {
  __shared__ float red[8];
  const int row = blockIdx.x, tid = threadIdx.x;
  const int w = tid >> 6;
  f32x4 f = *(const f32x4*)&x[(size_t)row * 1024 + tid * 4];
  float s = f[0] + f[1] + f[2] + f[3];
  float q = f[0] * f[0] + f[1] * f[1] + f[2] * f[2] + f[3] * f[3];
#pragma unroll
  for (int off = 1; off < 64; off <<= 1) {
    s += __shfl_xor(s, off);
    q += __shfl_xor(q, off);
  }
  if ((tid & 63) == 0) { red[w] = s; red[4 + w] = q; }
  __syncthreads();
  float S = red[0] + red[1] + red[2] + red[3];
  float Q = red[4] + red[5] + red[6] + red[7];
  float mu = S * (1.0f / 1024.0f);
  float var = Q * (1.0f / 1024.0f) - mu * mu;
  float rs = rsqrtf(var + 1e-6f);
  f32x4 scv = *(const f32x4*)&sc[tid * 4];
  f32x4 biv = *(const f32x4*)&bi[tid * 4];
  u16* o = xn + (size_t)row * 1024 + tid * 4;
#pragma unroll
  for (int j = 0; j < 4; j++) o[j] = f2bf((f[j] - mu) * rs * scv[j] + biv[j]);
}

// ---------------------------------------------------------------------------
// C[M][N] = A[M][K] * Bt[N][K]^T, bf16 in; out bf16 or fp32 (F32OUT).
// 128x128 tile, BK=64 (half the barriers of BK=32), XOR-swizzled LDS
// (logical 16B chunk c of row r lives at slot c^(r&7)) -> <=2-way conflicts.
template <bool F32OUT>
__global__ __launch_bounds__(256) void gemm_bt(const u16* __restrict__ A,
                                               const u16* __restrict__ Bt,
                                               void* __restrict__ Cp,
                                               int M, int N, int K) {
  __shared__ __attribute__((aligned(16))) u16 Als[128 * 64];
  __shared__ __attribute__((aligned(16))) u16 Bls[128 * 64];
  const int tid = threadIdx.x;
  const int w = tid >> 6, lane = tid & 63, ln = lane & 15, quad = lane >> 4;
  const int m0 = blockIdx.y * 128, n0 = blockIdx.x * 128;
  const int moff = (w & 1) * 64, noff = (w >> 1) * 64;
  const f32x4 fzero = {0.f, 0.f, 0.f, 0.f};
  f32x4 acc[4][4];
#pragma unroll
  for (int i = 0; i < 4; i++)
#pragma unroll
    for (int j = 0; j < 4; j++) acc[i][j] = fzero;

  // staging source bases: 4 chunks each for A and B per thread
  const u16* aS[4];
  const u16* bS[4];
#pragma unroll
  for (int i = 0; i < 4; i++) {
    int s = i * 256 + tid;
    int row = s >> 3, cs = (s & 7) ^ (row & 7);
    aS[i] = A + (size_t)(m0 + row) * K + cs * 8;
    bS[i] = Bt + (size_t)(n0 + row) * K + cs * 8;
  }

  for (int k0 = 0; k0 < K; k0 += 64) {
    __syncthreads();
#pragma unroll
    for (int i = 0; i < 4; i++) {
      int s = i * 256 + tid;
      gl_lds16(aS[i] + k0, &Als[s * 8]);
      gl_lds16(bS[i] + k0, &Bls[s * 8]);
    }
    __syncthreads();
#pragma unroll
    for (int kk = 0; kk < 2; kk++) {
      bf16x8 af[4], bfv[4];
#pragma unroll
      for (int mi = 0; mi < 4; mi++)
        af[mi] = *(const bf16x8*)
            &Als[(moff + mi * 16 + ln) * 64 + (((kk * 4 + quad) ^ (ln & 7)) * 8)];
#pragma unroll
      for (int ni = 0; ni < 4; ni++)
        bfv[ni] = *(const bf16x8*)
            &Bls[(noff + ni * 16 + ln) * 64 + (((kk * 4 + quad) ^ (ln & 7)) * 8)];
#pragma unroll
      for (int mi = 0; mi < 4; mi++)
#pragma unroll
        for (int ni = 0; ni < 4; ni++)
          acc[mi][ni] = __builtin_amdgcn_mfma_f32_16x16x32_bf16(af[mi], bfv[ni],
                                                                acc[mi][ni], 0, 0, 0);
    }
  }
#pragma unroll
  for (int mi = 0; mi < 4; mi++)
#pragma unroll
    for (int ni = 0; ni < 4; ni++)
#pragma unroll
      for (int r = 0; r < 4; r++) {
        size_t m = m0 + moff + mi * 16 + quad * 4 + r;
        size_t n = n0 + noff + ni * 16 + ln;
        if (F32OUT)
          ((float*)Cp)[m * N + n] = acc[mi][ni][r];
        else
          ((u16*)Cp)[m * N + n] = f2bf(acc[mi][ni][r]);
      }
}

// ---------------------------------------------------------------------------
// Per-head LN of q and k slices of qkv[8192][1536] (bf16); fp32 params.
// Q pre-scaled by 0.125*log2(e): scores directly in exp2 domain (fixed-max
// softmax is safe: LN'd q,k => |score| <= ~11.5).
__global__ __launch_bounds__(256) void qk_ln(const u16* __restrict__ qkv,
                                             const float* __restrict__ qs,
                                             const float* __restrict__ qb,
                                             const float* __restrict__ ks,
                                             const float* __restrict__ kb,
                                             u16* __restrict__ Q,
                                             u16* __restrict__ Kb) {
  const float SCL = 0.18033688011112042f;  // 0.125 * log2(e)
  const int m = blockIdx.x;
  const int b = m >> 11, n = m & 2047;
  const int tid = threadIdx.x, w = tid >> 6, lane = tid & 63;
  const u16* rowp = qkv + (size_t)m * 1536;
  const float qsc = qs[lane], qbi = qb[lane];
  const float ksc = ks[lane], kbi = kb[lane];
#pragma unroll
  for (int i = 0; i < 4; i++) {
    int h = w * 4 + i;
    float v = bf2f(rowp[h * 64 + lane]);
    float s = v, q2 = v * v;
#pragma unroll
    for (int off = 1; off < 64; off <<= 1) {
      s += __shfl_xor(s, off);
      q2 += __shfl_xor(q2, off);
    }
    float mu = s * (1.0f / 64.0f);
    float var = q2 * (1.0f / 64.0f) - mu * mu;
    float y = ((v - mu) * rsqrtf(var + 1e-6f) * qsc + qbi) * SCL;
    Q[((size_t)(b * 16 + h) * 2048 + n) * 64 + lane] = f2bf(y);
  }
  {
    int g = w;
    float v = bf2f(rowp[1024 + g * 64 + lane]);
    float s = v, q2 = v * v;
#pragma unroll
    for (int off = 1; off < 64; off <<= 1) {
      s += __shfl_xor(s, off);
      q2 += __shfl_xor(q2, off);
    }
    float mu = s * (1.0f / 64.0f);
    float var = q2 * (1.0f / 64.0f) - mu * mu;
    float y = (v - mu) * rsqrtf(var + 1e-6f) * ksc + kbi;
    Kb[((size_t)(b * 4 + g) * 2048 + n) * 64 + lane] = f2bf(y);
  }
}

// ---------------------------------------------------------------------------
// V transpose: qkv v-slice -> Vt [b][g][64][2048]. grid = (32, 16).
__global__ __launch_bounds__(256) void vtrans(const u16* __restrict__ qkv,
                                              u16* __restrict__ Vt) {
  __shared__ __attribute__((aligned(16))) u16 t[64 * 72];
  const int n0 = blockIdx.x * 64;
  const int bg = blockIdx.y;
  const int b = bg >> 2, g = bg & 3;
  const int tid = threadIdx.x;
  const u16* src = qkv + (size_t)(b * 2048 + n0) * 1536 + 1280 + g * 64;
#pragma unroll
  for (int i = 0; i < 2; i++) {
    int c = i * 256 + tid;
    int row = c >> 3, cc = c & 7;
    *(f32x4*)&t[row * 72 + cc * 8] = *(const f32x4*)&src[(size_t)row * 1536 + cc * 8];
  }
  __syncthreads();
  u16* dst = Vt + (size_t)bg * 64 * 2048 + n0;
#pragma unroll
  for (int i = 0; i < 2; i++) {
    int c = i * 256 + tid;
    int d = c >> 3, nc = c & 7;
    u16x8 o;
#pragma unroll
    for (int j = 0; j < 8; j++) o[j] = t[(nc * 8 + j) * 72 + d];
    *(u16x8*)&dst[(size_t)d * 2048 + nc * 8] = o;
  }
}

// ---------------------------------------------------------------------------
// Flash attention, transposed-S, fixed-max softmax, KT=64 keys/iter.
// grid = (16, 64), block = 256 (4 waves x 32 q-rows). LDS = 32 KB total
// (Kls 8K + Vls 8K + Pls 16K) -> 4 blocks/CU co-resident (grid is 4/CU).
// XOR chunk swizzle everywhere: logical chunk c of row r at slot c^(r&7).
__global__ __launch_bounds__(256) void attn(const u16* __restrict__ Q,
                                            const u16* __restrict__ Kb,
                                            const u16* __restrict__ Vt,
                                            u16* __restrict__ Out) {
  __shared__ __attribute__((aligned(16))) u16 Kls[64 * 64];    // [key][d]
  __shared__ __attribute__((aligned(16))) u16 Vls[64 * 64];    // [d][key]
  __shared__ __attribute__((aligned(16))) u16 Pls[4][32 * 64]; // per-wave [m][key]
  const int qt = blockIdx.x;
  const int bh = blockIdx.y;
  const int b = bh >> 4, h = bh & 15, g = h >> 2;
  const int tid = threadIdx.x, w = tid >> 6, lane = tid & 63;
  const int ln = lane & 15, quad = lane >> 4;
  const u16* Qg = Q + ((size_t)(b * 16 + h) * 2048 + qt * 128 + w * 32) * 64;
  const u16* Kg = Kb + (size_t)(b * 4 + g) * 2048 * 64;
  const u16* Vg = Vt + (size_t)(b * 4 + g) * 64 * 2048;
  const f32x4 fzero = {0.f, 0.f, 0.f, 0.f};

  // Q fragments (B-operand): rows m = mi*16+ln, k(d) = ks2*32 + quad*8
  bf16x8 qf[2][2];
#pragma unroll
  for (int mi = 0; mi < 2; mi++)
#pragma unroll
    for (int ks2 = 0; ks2 < 2; ks2++)
      qf[mi][ks2] = *(const bf16x8*)&Qg[(size_t)(mi * 16 + ln) * 64 + ks2 * 32 + quad * 8];

  f32x4 oacc[4][2];  // [ni(d-tile)][mi(m-tile)]
#pragma unroll
  for (int ni = 0; ni < 4; ni++)
#pragma unroll
    for (int mi = 0; mi < 2; mi++) oacc[ni][mi] = fzero;
  float lsum[2] = {0.f, 0.f};
  u16* Pw = &Pls[w][0];

  // staging geometry (constant per thread)
  const int sk0 = tid, sk1 = 256 + tid;
  const int krow0 = sk0 >> 3, kcs0 = (sk0 & 7) ^ (krow0 & 7);
  const int krow1 = sk1 >> 3, kcs1 = (sk1 & 7) ^ (krow1 & 7);

  for (int kt = 0; kt < 32; kt++) {
    __syncthreads();
    // K tile [64 keys][64 d]
    gl_lds16(Kg + (size_t)(kt * 64 + krow0) * 64 + kcs0 * 8, &Kls[sk0 * 8]);
    gl_lds16(Kg + (size_t)(kt * 64 + krow1) * 64 + kcs1 * 8, &Kls[sk1 * 8]);
    // V tile [64 d][64 keys]
    gl_lds16(Vg + (size_t)krow0 * 2048 + kt * 64 + kcs0 * 8, &Vls[sk0 * 8]);
    gl_lds16(Vg + (size_t)krow1 * 2048 + kt * 64 + kcs1 * 8, &Vls[sk1 * 8]);
    __syncthreads();

    // S^T: sacc[mi][ni][r] = S[key=ni*16+quad*4+r][m=mi*16+ln] (exp2 domain)
    f32x4 sacc[2][4];
#pragma unroll
    for (int ni = 0; ni < 4; ni++) {
      const int krow = ni * 16 + ln;
      bf16x8 kf0 = *(const bf16x8*)&Kls[krow * 64 + ((quad ^ (ln & 7)) * 8)];
      bf16x8 kf1 = *(const bf16x8*)&Kls[krow * 64 + (((4 + quad) ^ (ln & 7)) * 8)];
#pragma unroll
      for (int mi = 0; mi < 2; mi++) {
        f32x4 tt = __builtin_amdgcn_mfma_f32_16x16x32_bf16(kf0, qf[mi][0], fzero, 0, 0, 0);
        sacc[mi][ni] = __builtin_amdgcn_mfma_f32_16x16x32_bf16(kf1, qf[mi][1], tt, 0, 0, 0);
      }
    }

    // fixed-max softmax: p = exp2(s); row sums are per-lane (row m = ln)
#pragma unroll
    for (int mi = 0; mi < 2; mi++) {
      float ls = 0.f;
      const int mrow = mi * 16 + ln;
#pragma unroll
      for (int ni = 0; ni < 4; ni++) {
        float p0 = EXP2(sacc[mi][ni][0]);
        float p1 = EXP2(sacc[mi][ni][1]);
        float p2 = EXP2(sacc[mi][ni][2]);
        float p3 = EXP2(sacc[mi][ni][3]);
        ls += (p0 + p1) + (p2 + p3);
        bf16x4 pv = {(__bf16)p0, (__bf16)p1, (__bf16)p2, (__bf16)p3};
        // keys 16ni+4q+r -> chunk 2ni+(q>>1), slot ^(ln&7), 8B half (q&1)
        char* dst = (char*)&Pw[mrow * 64] +
                    (((2 * ni + (quad >> 1)) ^ (ln & 7)) * 16) + ((quad & 1) * 8);
        *(bf16x4*)dst = pv;
      }
      ls += __shfl_xor(ls, 16);
      ls += __shfl_xor(ls, 32);
      lsum[mi] += ls;
    }

    // O^T += Vt * P^T  (A = V rows d, B = P cols m); Pw is wave-private.
#pragma unroll
    for (int kc = 0; kc < 2; kc++) {
      bf16x8 pf[2];
#pragma unroll
      for (int mi = 0; mi < 2; mi++)
        pf[mi] = *(const bf16x8*)
            &Pw[(mi * 16 + ln) * 64 + (((4 * kc + quad) ^ (ln & 7)) * 8)];
#pragma unroll
      for (int ni = 0; ni < 4; ni++) {
        const int drow = ni * 16 + ln;
        bf16x8 vf = *(const bf16x8*)&Vls[drow * 64 + (((4 * kc + quad) ^ (ln & 7)) * 8)];
#pragma unroll
        for (int mi = 0; mi < 2; mi++)
          oacc[ni][mi] = __builtin_amdgcn_mfma_f32_16x16x32_bf16(vf, pf[mi],
                                                                 oacc[ni][mi], 0, 0, 0);
      }
    }
  }

  // epilogue: O[m][d] = O^T / lsum; row n = qt*128 + w*32 + mi*16 + ln
#pragma unroll
  for (int mi = 0; mi < 2; mi++) {
    float inv = 1.0f / lsum[mi];
    u16* Og = Out + ((size_t)b * 2048 + qt * 128 + w * 32 + mi * 16 + ln) * 1024 + h * 64;
#pragma unroll
    for (int ni = 0; ni < 4; ni++) {
      bf16x4 ov = {(__bf16)(oacc[ni][mi][0] * inv), (__bf16)(oacc[ni][mi][1] * inv),
                   (__bf16)(oacc[ni][mi][2] * inv), (__bf16)(oacc[ni][mi][3] * inv)};
      *(bf16x4*)&Og[ni * 16 + quad * 4] = ov;
    }
  }
}

// ---------------------------------------------------------------------------
extern "C" void kernel_launch(void* const* d_in, const int* in_sizes, int n_in,
                              void* d_out, int out_size, void* d_ws, size_t ws_size,
                              hipStream_t stream) {
  const float* x    = (const float*)d_in[0];
  const float* lns  = (const float*)d_in[1];
  const float* lnb  = (const float*)d_in[2];
  const float* Wq   = (const float*)d_in[3];
  const float* Wkv  = (const float*)d_in[4];
  const float* qns  = (const float*)d_in[5];
  const float* qnb  = (const float*)d_in[6];
  const float* kns  = (const float*)d_in[7];
  const float* knb  = (const float*)d_in[8];
  const float* Wout = (const float*)d_in[9];
  float* out = (float*)d_out;
  char* ws = (char*)d_ws;

  const size_t o_xn  = 0;                 // 16 MB: xn (bf16), later Qbuf
  const size_t o_qkv = 16777216;          // 24 MB: qkv (bf16), later attn_out
  const size_t o_bt  = o_qkv + 25165824;  // 3 MB: W^T (bf16), reused for Wout^T
  const size_t o_k   = o_bt + 3145728;    // 4 MB: Kbuf
  const size_t o_vt  = o_k + 4194304;     // 4 MB: Vtbuf
  u16* xn   = (u16*)(ws + o_xn);
  u16* qkv  = (u16*)(ws + o_qkv);
  u16* bt   = (u16*)(ws + o_bt);
  u16* Kbuf = (u16*)(ws + o_k);
  u16* Vtb  = (u16*)(ws + o_vt);
  u16* Qbuf = xn;    // xn dead after GEMM1
  u16* aout = qkv;   // qkv dead after qk_ln/vtrans

  transpose64<<<dim3(16, 16), 256, 0, stream>>>(Wq, bt, 1024);
  transpose64<<<dim3(16, 8), 256, 0, stream>>>(Wkv, bt + 1024 * 1024, 512);
  ln_x<<<8192, 256, 0, stream>>>(x, lns, lnb, xn);
  gemm_bt<false><<<dim3(12, 64), 256, 0, stream>>>(xn, bt, qkv, 8192, 1536, 1024);
  transpose64<<<dim3(16, 16), 256, 0, stream>>>(Wout, bt, 1024);
  qk_ln<<<8192, 256, 0, stream>>>(qkv, qns, qnb, kns, knb, Qbuf, Kbuf);
  vtrans<<<dim3(32, 16), 256, 0, stream>>>(qkv, Vtb);
  attn<<<dim3(16, 64), 256, 0, stream>>>(Qbuf, Kbuf, Vtb, aout);
  gemm_bt<true><<<dim3(8, 64), 256, 0, stream>>>(aout, bt, out, 8192, 1024, 1024);

  (void)in_sizes; (void)n_in; (void)out_size; (void)ws_size;
}